// Round 5
// baseline (389.392 us; speedup 1.0000x reference)
//
#include <hip/hip_runtime.h>
#include <math.h>

#define BB 4096
#define SEQ 50
#define KK 4
#define HH 64
#define NCOL (KK*SEQ)      // 200
#define NPART 64           // partial-sum groups over batch
#define BPP (BB/NPART)     // 64 batches per group

__device__ __forceinline__ float readlane_f32(float v, int lane) {
    return __int_as_float(__builtin_amdgcn_readlane(__float_as_int(v), lane));
}

// ---------------------------------------------------------------------------
// INIT: partial softmax denominators for iteration 0 (unshifted exp: |cw|
// stays < ~30 across iterations, exp fits fp32 comfortably) + zero the
// iter-1/2 partial accumulators. grid = NPART x 256; thread t < NCOL owns
// column t (coalesced across t).
// ---------------------------------------------------------------------------
__global__ void init_kernel(const float* __restrict__ cw,
                            float* __restrict__ part0,
                            float* __restrict__ part1,
                            float* __restrict__ part2) {
    const int p = blockIdx.x;
    const int t = threadIdx.x;
    if (t < NCOL) {
        const float* row = cw + (size_t)p * BPP * NCOL + t;
        float s = 0.f;
#pragma unroll 8
        for (int b = 0; b < BPP; b++) s += __expf(row[b * NCOL]);
        part0[p * NCOL + t] = s;
        part1[p * NCOL + t] = 0.f;
        part2[p * NCOL + t] = 0.f;
    }
}

// ---------------------------------------------------------------------------
// UPDATE: one routing iteration. grid = BB x 256; wave = k, lane = h.
// ALL cross-lane ops (readlane / shfl) execute with full exec: lanes
// h >= SEQ use a clamped seq index (hs=0) and compute discarded dummies;
// only the final stores/atomics are guarded. (Round-4 lesson: readlane
// inside divergent CF let the compiler predicate v's scaling -> lanes
// 50..63 held unscaled v -> wrong deltas.)
// delta: lane s re-reads x[b,s,k,:] (cache-hot, 16x float4) and dots it
// against v via readlane; binary-tree summation (matches R3 numerics).
// ---------------------------------------------------------------------------
template <int ITER>   // 0,1 = routing update; 2 = final (writes out)
__global__ void update_kernel(const float* __restrict__ cw_src,
                              float* __restrict__ cw_dst,
                              const float* __restrict__ x,
                              const int* __restrict__ mask,
                              const float* __restrict__ part_in,
                              float* __restrict__ part_out,
                              float* __restrict__ out) {
    const int b = blockIdx.x;
    const int k = threadIdx.x >> 6;
    const int h = threadIdx.x & 63;
    const int hs = (h < SEQ) ? h : 0;   // clamped seq index, keeps all lanes active

    __shared__ float scol[NCOL];

    // column denominators: thread t < NCOL sums NPART partials (L2-hot)
    if (threadIdx.x < NCOL) {
        float s = 0.f;
#pragma unroll 16
        for (int p = 0; p < NPART; p++) s += part_in[p * NCOL + threadIdx.x];
        scol[threadIdx.x] = s;
    }

    // all-lane loads (lanes >= SEQ load a redundant copy of column 0)
    const float c = cw_src[(size_t)b * NCOL + k * SEQ + hs];
    const int  mk = mask[b * SEQ + hs];

    __syncthreads();

    const float e = __expf(c) / scol[k * SEQ + hs];
    const float wlane = (h < SEQ && mk != 0) ? e : 0.f;   // branchless select

    // v_h = sum_s w_s * x[b,s,k,h]  (coalesced 256B wave-loads)
    const float* xp = x + (size_t)b * (SEQ * KK * HH) + k * HH + h;
    float v = 0.f;
#pragma unroll
    for (int s = 0; s < SEQ; s++)
        v = fmaf(readlane_f32(wlane, s), xp[s * (KK * HH)], v);

    // squash: n2 = ||v||^2 (6 shfls, all lanes)
    float n2 = v * v;
#pragma unroll
    for (int off = 32; off >= 1; off >>= 1) n2 += __shfl_xor(n2, off, 64);
    const float scalar = n2 / ((1.f + n2) * sqrtf(n2 + 1e-9f));
    v *= scalar;

    if (ITER == 2) {
        out[(size_t)b * (KK * HH) + k * HH + h] = v;
    } else {
        // delta_s = x[b,s,k,:] . v at lane s. ALL lanes run the dot
        // (clamped row for h >= SEQ); binary-tree summation.
        const float* xt = x + (size_t)b * (SEQ * KK * HH) + hs * (KK * HH) + k * HH;
        float g[16];
#pragma unroll
        for (int j4 = 0; j4 < 16; j4++) {
            const float4 xv = *(const float4*)(xt + j4 * 4);
            const float p0 = xv.x * readlane_f32(v, 4 * j4 + 0);
            const float p1 = xv.y * readlane_f32(v, 4 * j4 + 1);
            const float p2 = xv.z * readlane_f32(v, 4 * j4 + 2);
            const float p3 = xv.w * readlane_f32(v, 4 * j4 + 3);
            g[j4] = (p0 + p1) + (p2 + p3);
        }
        float t8[8], t4[4], t2[2];
#pragma unroll
        for (int i = 0; i < 8; i++) t8[i] = g[2 * i] + g[2 * i + 1];
#pragma unroll
        for (int i = 0; i < 4; i++) t4[i] = t8[2 * i] + t8[2 * i + 1];
#pragma unroll
        for (int i = 0; i < 2; i++) t2[i] = t4[2 * i] + t4[2 * i + 1];
        const float del = t2[0] + t2[1];

        if (h < SEQ) {
            const float nc = c + del;
            cw_dst[(size_t)b * NCOL + k * SEQ + h] = nc;
            atomicAdd(&part_out[(b >> 6) * NCOL + k * SEQ + h], __expf(nc));
        }
    }
}

extern "C" void kernel_launch(void* const* d_in, const int* in_sizes, int n_in,
                              void* d_out, int out_size, void* d_ws, size_t ws_size,
                              hipStream_t stream) {
    const int*   mask  = (const int*)d_in[0];
    const float* x     = (const float*)d_in[1];
    const float* cw_in = (const float*)d_in[2];
    float* out = (float*)d_out;

    float* cw_ws = (float*)d_ws;                       // BB*NCOL floats
    float* part0 = cw_ws + (size_t)BB * NCOL;          // NPART*NCOL
    float* part1 = part0 + NPART * NCOL;
    float* part2 = part1 + NPART * NCOL;

    init_kernel<<<NPART, 256, 0, stream>>>(cw_in, part0, part1, part2);
    update_kernel<0><<<BB, 256, 0, stream>>>(cw_in, cw_ws, x, mask, part0, part1, nullptr);
    update_kernel<1><<<BB, 256, 0, stream>>>(cw_ws, cw_ws, x, mask, part1, part2, nullptr);
    update_kernel<2><<<BB, 256, 0, stream>>>(cw_ws, nullptr, x, mask, part2, nullptr, out);
}